// Round 3
// baseline (926.210 us; speedup 1.0000x reference)
//
#include <hip/hip_runtime.h>

// GCN 2-layer, CSR-gather formulation, bucketed CSR build (L2-resident scatters).
// N=250000 nodes, E=4000000 edges, 18 -> 16 -> 1.
//
// hs1[n] = (x[n] @ W1) * dis[n]         (dis = rsqrt(deg+1), deg = in-degree)
// layer1: relu(dis[n]*(sum_{s->n} hs1[s] + hs1[n]) + b1)
// hs2[n] = (layer1 @ W2) * dis[n]
// out[n] = dis[n]*(sum_{s->n} hs2[s] + hs2[n]) + b2
//
// CSR build: histogram -> scan -> bucket-append pairs (dense writes) ->
// per-bucket placement (csr region ~8KB, pos region 512B: L2-resident).

#define TPB 256
#define CHUNK 1024       // scan elements per block (256 threads x 4)
#define BBITS 7          // 128 nodes per bucket
#define BNODES (1 << BBITS)

__global__ void hist_kernel(const int* __restrict__ dst, int* __restrict__ deg, int E) {
    int e = blockIdx.x * blockDim.x + threadIdx.x;
    if (e < E) atomicAdd(&deg[dst[e]], 1);
}

// per-chunk sums
__global__ void scan1_kernel(const int* __restrict__ deg, int* __restrict__ cs, int N) {
    __shared__ int s[TPB];
    int t = threadIdx.x;
    int base = blockIdx.x * CHUNK + t * 4;
    int sum = 0;
#pragma unroll
    for (int k = 0; k < 4; k++) {
        int i = base + k;
        sum += (i < N) ? deg[i] : 0;
    }
    s[t] = sum;
    __syncthreads();
    for (int off = TPB / 2; off > 0; off >>= 1) {
        if (t < off) s[t] += s[t + off];
        __syncthreads();
    }
    if (t == 0) cs[blockIdx.x] = s[0];
}

// exclusive scan of chunk sums in-place (supports C <= 1024)
__global__ void scan2_kernel(int* __restrict__ cs, int C) {
    __shared__ int s[TPB];
    int t = threadIdx.x;
    int v[4];
    int sum = 0;
#pragma unroll
    for (int k = 0; k < 4; k++) {
        int i = t * 4 + k;
        v[k] = (i < C) ? cs[i] : 0;
        sum += v[k];
    }
    s[t] = sum;
    __syncthreads();
    for (int off = 1; off < TPB; off <<= 1) {
        int add = (t >= off) ? s[t - off] : 0;
        __syncthreads();
        s[t] += add;
        __syncthreads();
    }
    int run = s[t] - sum;  // exclusive
#pragma unroll
    for (int k = 0; k < 4; k++) {
        int i = t * 4 + k;
        if (i < C) cs[i] = run;
        run += v[k];
    }
}

// per-element exclusive scan -> pos (row starts)
__global__ void scan3_kernel(const int* __restrict__ deg, const int* __restrict__ cs,
                             int* __restrict__ pos, int N) {
    __shared__ int s[TPB];
    int t = threadIdx.x;
    int base = blockIdx.x * CHUNK + t * 4;
    int v[4];
    int sum = 0;
#pragma unroll
    for (int k = 0; k < 4; k++) {
        int i = base + k;
        v[k] = (i < N) ? deg[i] : 0;
        sum += v[k];
    }
    s[t] = sum;
    __syncthreads();
    for (int off = 1; off < TPB; off <<= 1) {
        int add = (t >= off) ? s[t - off] : 0;
        __syncthreads();
        s[t] += add;
        __syncthreads();
    }
    int run = cs[blockIdx.x] + s[t] - sum;
#pragma unroll
    for (int k = 0; k < 4; k++) {
        int i = base + k;
        if (i < N) pos[i] = run;
        run += v[k];
    }
}

// cursor[b] = start of bucket b's edge region = pos[b*BNODES]
__global__ void cursor_init_kernel(const int* __restrict__ pos, int* __restrict__ cursor,
                                   int NB, int N) {
    int b = blockIdx.x * blockDim.x + threadIdx.x;
    if (b < NB) cursor[b] = pos[b << BBITS];  // b*BNODES < N by construction
}

// phase A: append packed (src<<BBITS | dst_local) into bucket-ordered pairs
__global__ void binA_kernel(const int* __restrict__ src, const int* __restrict__ dst,
                            int* __restrict__ cursor, int* __restrict__ pairs, int E) {
    int e = blockIdx.x * blockDim.x + threadIdx.x;
    if (e >= E) return;
    int d = dst[e];
    int s = src[e];
    int p = atomicAdd(&cursor[d >> BBITS], 1);
    pairs[p] = (s << BBITS) | (d & (BNODES - 1));
}

// phase B: one block per bucket; scatter into L2-resident csr region.
// After phase A, cursor[b] = end of bucket b's region (= start of b+1).
__global__ void binB_kernel(const int* __restrict__ cursor, const int* __restrict__ pairs,
                            int* __restrict__ pos, int* __restrict__ csr) {
    int b = blockIdx.x;
    int estart = (b == 0) ? 0 : cursor[b - 1];
    int eend = cursor[b];
    for (int e = estart + threadIdx.x; e < eend; e += blockDim.x) {
        int v = pairs[e];
        int d = (b << BBITS) | (v & (BNODES - 1));
        int s = v >> BBITS;
        int p = atomicAdd(&pos[d], 1);
        csr[p] = s;
    }
}

// hs1[n,f] = (x[n] @ W1)[f] * dis[n]
__global__ void h1_kernel(const float* __restrict__ x, const float* __restrict__ W1,
                          const int* __restrict__ deg, float* __restrict__ hs1, int N) {
    __shared__ float w[18 * 16];
    for (int i = threadIdx.x; i < 18 * 16; i += blockDim.x) w[i] = W1[i];
    __syncthreads();
    int n = blockIdx.x * blockDim.x + threadIdx.x;
    if (n >= N) return;
    float xv[18];
#pragma unroll
    for (int k = 0; k < 18; k++) xv[k] = x[n * 18 + k];
    float d = rsqrtf((float)deg[n] + 1.0f);
    float acc[16];
#pragma unroll
    for (int f = 0; f < 16; f++) acc[f] = 0.0f;
#pragma unroll
    for (int k = 0; k < 18; k++) {
        float xk = xv[k];
#pragma unroll
        for (int f = 0; f < 16; f++) acc[f] = fmaf(xk, w[k * 16 + f], acc[f]);
    }
    float4* out = (float4*)(hs1 + (size_t)n * 16);
#pragma unroll
    for (int q = 0; q < 4; q++) {
        float4 v;
        v.x = acc[q * 4 + 0] * d;
        v.y = acc[q * 4 + 1] * d;
        v.z = acc[q * 4 + 2] * d;
        v.w = acc[q * 4 + 3] * d;
        out[q] = v;
    }
}

// layer-1 aggregate + relu + W2 dot, fused. 4 lanes per node (one float4 quad each).
__global__ void agg1_kernel(const int* __restrict__ csr, const int* __restrict__ pos,
                            const int* __restrict__ deg, const float* __restrict__ hs1,
                            const float* __restrict__ b1, const float* __restrict__ W2,
                            float* __restrict__ hs2, int N) {
    int tid = blockIdx.x * blockDim.x + threadIdx.x;
    int node = tid >> 2;
    int q = tid & 3;
    if (node >= N) return;
    int end = pos[node];
    int dg = deg[node];
    const float4* h4 = (const float4*)hs1;
    float4 acc = make_float4(0.f, 0.f, 0.f, 0.f);
    for (int j = end - dg; j < end; j++) {
        int s = csr[j];
        float4 v = h4[(size_t)s * 4 + q];
        acc.x += v.x; acc.y += v.y; acc.z += v.z; acc.w += v.w;
    }
    float4 self = h4[(size_t)node * 4 + q];
    float d = rsqrtf((float)dg + 1.0f);
    float4 bb = ((const float4*)b1)[q];
    float4 ww = ((const float4*)W2)[q];
    float p = fmaxf(d * (acc.x + self.x) + bb.x, 0.f) * ww.x;
    p      += fmaxf(d * (acc.y + self.y) + bb.y, 0.f) * ww.y;
    p      += fmaxf(d * (acc.z + self.z) + bb.z, 0.f) * ww.z;
    p      += fmaxf(d * (acc.w + self.w) + bb.w, 0.f) * ww.w;
    p += __shfl_xor(p, 1);
    p += __shfl_xor(p, 2);
    if (q == 0) hs2[node] = p * d;
}

// layer-2 aggregate + bias, fused. Thread per node (1 feature).
__global__ void agg2_kernel(const int* __restrict__ csr, const int* __restrict__ pos,
                            const int* __restrict__ deg, const float* __restrict__ hs2,
                            const float* __restrict__ b2, float* __restrict__ out, int N) {
    int n = blockIdx.x * blockDim.x + threadIdx.x;
    if (n >= N) return;
    int end = pos[n];
    int dg = deg[n];
    float acc = 0.f;
    for (int j = end - dg; j < end; j++) acc += hs2[csr[j]];
    float d = rsqrtf((float)dg + 1.0f);
    out[n] = d * (acc + hs2[n]) + b2[0];
}

extern "C" void kernel_launch(void* const* d_in, const int* in_sizes, int n_in,
                              void* d_out, int out_size, void* d_ws, size_t ws_size,
                              hipStream_t stream) {
    const float* x = (const float*)d_in[0];
    const int* edge_index = (const int*)d_in[1];
    const float* W1 = (const float*)d_in[2];
    const float* b1 = (const float*)d_in[3];
    const float* W2 = (const float*)d_in[4];
    const float* b2 = (const float*)d_in[5];
    float* out = (float*)d_out;

    const int N = in_sizes[0] / 18;
    const int E = in_sizes[1] / 2;
    const int* src = edge_index;
    const int* dst = edge_index + E;
    const int NB = (N + BNODES - 1) / BNODES;  // 1954 buckets

    // workspace layout (4B words), total = 19N + E = 35 MB:
    // [0, N)           deg (int, zeroed)
    // [N, 2N)          pos (int)  -- row starts, becomes row ends after binB
    // [2N, 2N+E)       csr (int)  -- chunk_sums aliases its head (pre-fill lifetime)
    // [2N+E, 18N+E)    hs1 (float, 16N) -- pairs (E ints <= 16N) aliases it (pre-h1)
    // [18N+E, 19N+E)   hs2 (float, N) -- cursor (NB ints) aliases it (pre-agg1)
    int* ws = (int*)d_ws;
    int* deg = ws;
    int* pos = ws + N;
    int* csr = ws + 2 * (size_t)N;
    int* chunk_sums = csr;
    int* pairs = ws + 2 * (size_t)N + E;
    float* hs1 = (float*)pairs;
    float* hs2 = hs1 + 16 * (size_t)N;
    int* cursor = (int*)hs2;

    hipMemsetAsync(deg, 0, (size_t)N * sizeof(int), stream);

    int nBlocksE = (E + TPB - 1) / TPB;
    int nBlocksN = (N + TPB - 1) / TPB;
    int C = (N + CHUNK - 1) / CHUNK;  // 245 chunks, scan2 supports <= 1024

    hist_kernel<<<nBlocksE, TPB, 0, stream>>>(dst, deg, E);
    scan1_kernel<<<C, TPB, 0, stream>>>(deg, chunk_sums, N);
    scan2_kernel<<<1, TPB, 0, stream>>>(chunk_sums, C);
    scan3_kernel<<<C, TPB, 0, stream>>>(deg, chunk_sums, pos, N);
    cursor_init_kernel<<<(NB + TPB - 1) / TPB, TPB, 0, stream>>>(pos, cursor, NB, N);
    binA_kernel<<<nBlocksE, TPB, 0, stream>>>(src, dst, cursor, pairs, E);
    binB_kernel<<<NB, TPB, 0, stream>>>(cursor, pairs, pos, csr);
    h1_kernel<<<nBlocksN, TPB, 0, stream>>>(x, W1, deg, hs1, N);
    agg1_kernel<<<(4 * N + TPB - 1) / TPB, TPB, 0, stream>>>(csr, pos, deg, hs1, b1, W2, hs2, N);
    agg2_kernel<<<nBlocksN, TPB, 0, stream>>>(csr, pos, deg, hs2, b2, out, N);
}

// Round 4
// 547.552 us; speedup vs baseline: 1.6915x; 1.6915x over previous
//
#include <hip/hip_runtime.h>

// GCN 2-layer. N=250000, E=4000000, 18 -> 16 -> 1.
// Bucket-binned edge list (1024 dst nodes/bucket, NB=245) + per-bucket LDS
// accumulators. No fp global atomics; no fine CSR; all scatter targets are
// block-private (single XCD) to avoid cross-XCD partial-line writeback.
//
// out[d] = dis[d] * (sum_{s->d} hs[s] + hs[d]) + bias, hs pre-scaled by dis.

#define NB_BITS 10
#define BN (1 << NB_BITS)       // 1024 nodes per bucket
#define BIN_TPB 256
#define BIN_CHUNK 8192
#define AGG_TPB 1024

// per-block LDS histogram of dst buckets -> global bcnt (one add per block*bucket)
__global__ void bhist_kernel(const int* __restrict__ dst, int* __restrict__ bcnt, int E) {
    __shared__ int cnt[256];
    int t = threadIdx.x;
    cnt[t] = 0;
    __syncthreads();
    int base = blockIdx.x * BIN_CHUNK;
    int end = min(base + BIN_CHUNK, E);
    for (int e = base + t; e < end; e += BIN_TPB)
        atomicAdd(&cnt[dst[e] >> NB_BITS], 1);
    __syncthreads();
    if (cnt[t] > 0) atomicAdd(&bcnt[t], cnt[t]);
}

// exclusive scan of bcnt[256] -> bstart, cursor (NB=245 <= 256)
__global__ void bscan_kernel(const int* __restrict__ bcnt, int* __restrict__ bstart,
                             int* __restrict__ cursor) {
    __shared__ int s[256];
    int t = threadIdx.x;
    int v = bcnt[t];
    s[t] = v;
    __syncthreads();
    for (int off = 1; off < 256; off <<= 1) {
        int add = (t >= off) ? s[t - off] : 0;
        __syncthreads();
        s[t] += add;
        __syncthreads();
    }
    int excl = s[t] - v;
    bstart[t] = excl;       // for t >= NB this equals E (total), so bstart[NB] = E
    cursor[t] = excl;
}

// place edges: block reserves a private contiguous range per bucket, writes
// packed (src<<10 | dst&1023) via LDS cursors. All lines single-block-owned.
__global__ void bplace_kernel(const int* __restrict__ src, const int* __restrict__ dst,
                              int* __restrict__ cursor, int* __restrict__ pairs, int E) {
    __shared__ int cnt[256];
    __shared__ int lofs[256];
    int t = threadIdx.x;
    cnt[t] = 0;
    __syncthreads();
    int base = blockIdx.x * BIN_CHUNK;
    int end = min(base + BIN_CHUNK, E);
    for (int e = base + t; e < end; e += BIN_TPB)
        atomicAdd(&cnt[dst[e] >> NB_BITS], 1);
    __syncthreads();
    if (cnt[t] > 0) lofs[t] = atomicAdd(&cursor[t], cnt[t]);
    __syncthreads();
    for (int e = base + t; e < end; e += BIN_TPB) {
        int d = dst[e];
        int sv = src[e];
        int b = d >> NB_BITS;
        int p = atomicAdd(&lofs[b], 1);
        pairs[p] = (sv << NB_BITS) | (d & (BN - 1));
    }
}

// per-bucket in-degree via LDS counters -> dis = rsqrt(deg+1)
__global__ void degdis_kernel(const int* __restrict__ pairs, const int* __restrict__ bstart,
                              float* __restrict__ dis, int N) {
    __shared__ int cnt[BN];
    int b = blockIdx.x, t = threadIdx.x;
    for (int i = t; i < BN; i += blockDim.x) cnt[i] = 0;
    __syncthreads();
    int s0 = bstart[b], s1 = bstart[b + 1];
    for (int e = s0 + t; e < s1; e += blockDim.x)
        atomicAdd(&cnt[pairs[e] & (BN - 1)], 1);
    __syncthreads();
    int nbase = b << NB_BITS;
    for (int i = t; i < BN; i += blockDim.x) {
        int n = nbase + i;
        if (n < N) dis[n] = rsqrtf((float)cnt[i] + 1.0f);
    }
}

// hs1[n,f] = (x[n] @ W1)[f] * dis[n]
__global__ void h1_kernel(const float* __restrict__ x, const float* __restrict__ W1,
                          const float* __restrict__ dis, float* __restrict__ hs1, int N) {
    __shared__ float w[18 * 16];
    for (int i = threadIdx.x; i < 18 * 16; i += blockDim.x) w[i] = W1[i];
    __syncthreads();
    int n = blockIdx.x * blockDim.x + threadIdx.x;
    if (n >= N) return;
    const float2* x2 = (const float2*)(x + (size_t)n * 18);  // 72B rows, 8B-aligned
    float xv[18];
#pragma unroll
    for (int k = 0; k < 9; k++) {
        float2 v = x2[k];
        xv[2 * k] = v.x;
        xv[2 * k + 1] = v.y;
    }
    float d = dis[n];
    float acc[16];
#pragma unroll
    for (int f = 0; f < 16; f++) acc[f] = 0.0f;
#pragma unroll
    for (int k = 0; k < 18; k++) {
        float xk = xv[k];
#pragma unroll
        for (int f = 0; f < 16; f++) acc[f] = fmaf(xk, w[k * 16 + f], acc[f]);
    }
    float4* outp = (float4*)(hs1 + (size_t)n * 16);
#pragma unroll
    for (int q = 0; q < 4; q++) {
        float4 v;
        v.x = acc[q * 4 + 0] * d;
        v.y = acc[q * 4 + 1] * d;
        v.z = acc[q * 4 + 2] * d;
        v.w = acc[q * 4 + 3] * d;
        outp[q] = v;
    }
}

// layer-1: per-bucket LDS accumulate (16 lanes/edge, banks spread over f),
// epilogue: relu + W2 dot + dis scale -> hs2
__global__ void agg1_kernel(const int* __restrict__ pairs, const int* __restrict__ bstart,
                            const float* __restrict__ hs1, const float* __restrict__ dis,
                            const float* __restrict__ b1, const float* __restrict__ W2,
                            float* __restrict__ hs2, int N) {
    __shared__ float acc[BN * 16];  // 64 KB
    int b = blockIdx.x, t = threadIdx.x;
    for (int i = t; i < BN * 16; i += AGG_TPB) acc[i] = 0.f;
    __syncthreads();
    int s0 = bstart[b], s1 = bstart[b + 1];
    int nit = (s1 - s0) << 4;
    int f = t & 15;
    for (int w = t; w < nit; w += AGG_TPB) {
        int e = s0 + (w >> 4);
        int pv = pairs[e];                 // broadcast across 16 lanes
        int srcn = pv >> NB_BITS;
        int dl = pv & (BN - 1);
        atomicAdd(&acc[dl * 16 + f], hs1[(size_t)srcn * 16 + f]);
    }
    __syncthreads();
    int nbase = b << NB_BITS;
    float bbf = b1[f], wwf = W2[f];
    for (int nl = t >> 4; nl < BN; nl += AGG_TPB / 16) {
        int n = nbase + nl;
        float d = 0.f, p = 0.f;
        if (n < N) {
            d = dis[n];
            float self = hs1[(size_t)n * 16 + f];
            float v = fmaxf(d * (acc[nl * 16 + f] + self) + bbf, 0.f);
            p = v * wwf;
        }
        p += __shfl_xor(p, 1);
        p += __shfl_xor(p, 2);
        p += __shfl_xor(p, 4);
        p += __shfl_xor(p, 8);
        if (f == 0 && n < N) hs2[n] = p * d;
    }
}

// layer-2: per-bucket LDS accumulate of hs2, epilogue adds self + bias
__global__ void agg2_kernel(const int* __restrict__ pairs, const int* __restrict__ bstart,
                            const float* __restrict__ hs2, const float* __restrict__ dis,
                            const float* __restrict__ b2, float* __restrict__ out, int N) {
    __shared__ float acc[BN];
    int b = blockIdx.x, t = threadIdx.x;
    for (int i = t; i < BN; i += blockDim.x) acc[i] = 0.f;
    __syncthreads();
    int s0 = bstart[b], s1 = bstart[b + 1];
    for (int e = s0 + t; e < s1; e += blockDim.x) {
        int pv = pairs[e];
        atomicAdd(&acc[pv & (BN - 1)], hs2[pv >> NB_BITS]);
    }
    __syncthreads();
    int nbase = b << NB_BITS;
    for (int i = t; i < BN; i += blockDim.x) {
        int n = nbase + i;
        if (n < N) out[n] = dis[n] * (acc[i] + hs2[n]) + b2[0];
    }
}

extern "C" void kernel_launch(void* const* d_in, const int* in_sizes, int n_in,
                              void* d_out, int out_size, void* d_ws, size_t ws_size,
                              hipStream_t stream) {
    const float* x = (const float*)d_in[0];
    const int* edge_index = (const int*)d_in[1];
    const float* W1 = (const float*)d_in[2];
    const float* b1 = (const float*)d_in[3];
    const float* W2 = (const float*)d_in[4];
    const float* b2 = (const float*)d_in[5];
    float* out = (float*)d_out;

    const int N = in_sizes[0] / 18;
    const int E = in_sizes[1] / 2;
    const int* src = edge_index;
    const int* dst = edge_index + E;
    const int NB = (N + BN - 1) / BN;  // 245

    // ws layout (4B words), total = E + 18N + 769 ~= 34.0 MB:
    // [0, E)              pairs
    // [E, E+16N)          hs1   (16B-aligned: E = 4M)
    // [E+16N, E+17N)      hs2
    // [E+17N, E+18N)      dis
    // then bstart[257], cursor[256], bcnt[256]
    int* ws = (int*)d_ws;
    int* pairs = ws;
    float* hs1 = (float*)(ws + (size_t)E);
    float* hs2 = hs1 + (size_t)16 * N;
    float* dis = hs2 + N;
    int* bstart = (int*)(dis + N);
    int* cursor = bstart + 257;
    int* bcnt = cursor + 256;

    hipMemsetAsync(bcnt, 0, 256 * sizeof(int), stream);

    int binBlocks = (E + BIN_CHUNK - 1) / BIN_CHUNK;  // 489
    int nBlocksN = (N + BIN_TPB - 1) / BIN_TPB;

    bhist_kernel<<<binBlocks, BIN_TPB, 0, stream>>>(dst, bcnt, E);
    bscan_kernel<<<1, 256, 0, stream>>>(bcnt, bstart, cursor);
    bplace_kernel<<<binBlocks, BIN_TPB, 0, stream>>>(src, dst, cursor, pairs, E);
    degdis_kernel<<<NB, 512, 0, stream>>>(pairs, bstart, dis, N);
    h1_kernel<<<nBlocksN, BIN_TPB, 0, stream>>>(x, W1, dis, hs1, N);
    agg1_kernel<<<NB, AGG_TPB, 0, stream>>>(pairs, bstart, hs1, dis, b1, W2, hs2, N);
    agg2_kernel<<<NB, 512, 0, stream>>>(pairs, bstart, hs2, dis, b2, out, N);
}

// Round 5
// 541.499 us; speedup vs baseline: 1.7105x; 1.0112x over previous
//
#include <hip/hip_runtime.h>

// GCN 2-layer. N=250000, E=4000000, 18 -> 16 -> 1.
// Bucket-binned edge list (512 dst nodes/bucket, NB=489) + per-bucket LDS
// accumulators. No fp global atomics; all scatter targets block-private.
// Gather loops 8x unrolled for memory-level parallelism (R4 was latency-bound:
// 620 GB/s effective, VALUBusy 5.8% -- serial pairs->gather->atomic chain).
//
// out[d] = dis[d] * (sum_{s->d} hs[s] + hs[d]) + bias, hs pre-scaled by dis.

#define NB_BITS 9
#define BN (1 << NB_BITS)       // 512 nodes per bucket
#define BIN_TPB 512
#define BIN_CHUNK 8192
#define AGG_TPB 512
#define ASTRIDE 17              // LDS pad: kills bank aliasing on acc
#define UF 8

// per-block LDS histogram of dst buckets -> global bcnt
__global__ void bhist_kernel(const int* __restrict__ dst, int* __restrict__ bcnt, int E) {
    __shared__ int cnt[BN];
    int t = threadIdx.x;
    for (int i = t; i < BN; i += BIN_TPB) cnt[i] = 0;
    __syncthreads();
    int base = blockIdx.x * BIN_CHUNK;
    int end = min(base + BIN_CHUNK, E);
#pragma unroll 4
    for (int e = base + t; e < end; e += BIN_TPB)
        atomicAdd(&cnt[dst[e] >> NB_BITS], 1);
    __syncthreads();
    for (int i = t; i < BN; i += BIN_TPB)
        if (cnt[i] > 0) atomicAdd(&bcnt[i], cnt[i]);
}

// exclusive scan of bcnt[BN] -> bstart, cursor
__global__ void bscan_kernel(const int* __restrict__ bcnt, int* __restrict__ bstart,
                             int* __restrict__ cursor) {
    __shared__ int s[BN];
    int t = threadIdx.x;  // BN threads
    int v = bcnt[t];
    s[t] = v;
    __syncthreads();
    for (int off = 1; off < BN; off <<= 1) {
        int add = (t >= off) ? s[t - off] : 0;
        __syncthreads();
        s[t] += add;
        __syncthreads();
    }
    int excl = s[t] - v;
    bstart[t] = excl;           // for t >= NB this equals E, so bstart[NB] = E
    cursor[t] = excl;
    if (t == BN - 1) bstart[BN] = s[t];
}

// place edges: block reserves private contiguous range per bucket, writes
// packed (src<<9 | dst&511) via LDS cursors. All lines single-block-owned.
__global__ void bplace_kernel(const int* __restrict__ src, const int* __restrict__ dst,
                              int* __restrict__ cursor, int* __restrict__ pairs, int E) {
    __shared__ int cnt[BN];
    __shared__ int lofs[BN];
    int t = threadIdx.x;
    for (int i = t; i < BN; i += BIN_TPB) cnt[i] = 0;
    __syncthreads();
    int base = blockIdx.x * BIN_CHUNK;
    int end = min(base + BIN_CHUNK, E);
#pragma unroll 4
    for (int e = base + t; e < end; e += BIN_TPB)
        atomicAdd(&cnt[dst[e] >> NB_BITS], 1);
    __syncthreads();
    for (int i = t; i < BN; i += BIN_TPB)
        if (cnt[i] > 0) lofs[i] = atomicAdd(&cursor[i], cnt[i]);
    __syncthreads();
#pragma unroll 4
    for (int e = base + t; e < end; e += BIN_TPB) {
        int d = dst[e];
        int sv = src[e];
        int b = d >> NB_BITS;
        int p = atomicAdd(&lofs[b], 1);
        pairs[p] = (sv << NB_BITS) | (d & (BN - 1));
    }
}

// per-bucket in-degree via LDS counters -> dis = rsqrt(deg+1)
__global__ void degdis_kernel(const int* __restrict__ pairs, const int* __restrict__ bstart,
                              float* __restrict__ dis, int N) {
    __shared__ int cnt[BN];
    int b = blockIdx.x, t = threadIdx.x;
    for (int i = t; i < BN; i += blockDim.x) cnt[i] = 0;
    __syncthreads();
    int s0 = bstart[b], s1 = bstart[b + 1];
#pragma unroll 4
    for (int e = s0 + t; e < s1; e += blockDim.x)
        atomicAdd(&cnt[pairs[e] & (BN - 1)], 1);
    __syncthreads();
    int nbase = b << NB_BITS;
    for (int i = t; i < BN; i += blockDim.x) {
        int n = nbase + i;
        if (n < N) dis[n] = rsqrtf((float)cnt[i] + 1.0f);
    }
}

// hs1[n,f] = (x[n] @ W1)[f] * dis[n]
__global__ void h1_kernel(const float* __restrict__ x, const float* __restrict__ W1,
                          const float* __restrict__ dis, float* __restrict__ hs1, int N) {
    __shared__ float w[18 * 16];
    for (int i = threadIdx.x; i < 18 * 16; i += blockDim.x) w[i] = W1[i];
    __syncthreads();
    int n = blockIdx.x * blockDim.x + threadIdx.x;
    if (n >= N) return;
    const float2* x2 = (const float2*)(x + (size_t)n * 18);
    float xv[18];
#pragma unroll
    for (int k = 0; k < 9; k++) {
        float2 v = x2[k];
        xv[2 * k] = v.x;
        xv[2 * k + 1] = v.y;
    }
    float d = dis[n];
    float acc[16];
#pragma unroll
    for (int f = 0; f < 16; f++) acc[f] = 0.0f;
#pragma unroll
    for (int k = 0; k < 18; k++) {
        float xk = xv[k];
#pragma unroll
        for (int f = 0; f < 16; f++) acc[f] = fmaf(xk, w[k * 16 + f], acc[f]);
    }
    float4* outp = (float4*)(hs1 + (size_t)n * 16);
#pragma unroll
    for (int q = 0; q < 4; q++) {
        float4 v;
        v.x = acc[q * 4 + 0] * d;
        v.y = acc[q * 4 + 1] * d;
        v.z = acc[q * 4 + 2] * d;
        v.w = acc[q * 4 + 3] * d;
        outp[q] = v;
    }
}

// layer-1: per-bucket LDS accumulate (16 lanes/edge), 8x-unrolled gather.
// epilogue: relu + W2 dot + dis scale -> hs2
__global__ void agg1_kernel(const int* __restrict__ pairs, const int* __restrict__ bstart,
                            const float* __restrict__ hs1, const float* __restrict__ dis,
                            const float* __restrict__ b1, const float* __restrict__ W2,
                            float* __restrict__ hs2, int N) {
    __shared__ float acc[BN * ASTRIDE];  // ~34.8 KB
    int b = blockIdx.x, t = threadIdx.x;
    for (int i = t; i < BN * ASTRIDE; i += AGG_TPB) acc[i] = 0.f;
    __syncthreads();
    int s0 = bstart[b], s1 = bstart[b + 1];
    int f = t & 15;
    const int G = AGG_TPB / 16;  // 32 edge-groups
    int e = s0 + (t >> 4);
    // main: 8 independent pairs loads -> 8 independent gathers -> 8 LDS atomics
    for (; e + (UF - 1) * G < s1; e += UF * G) {
        int pv[UF];
        float v[UF];
#pragma unroll
        for (int u = 0; u < UF; u++) pv[u] = pairs[e + u * G];
#pragma unroll
        for (int u = 0; u < UF; u++) v[u] = hs1[(size_t)(pv[u] >> NB_BITS) * 16 + f];
#pragma unroll
        for (int u = 0; u < UF; u++) atomicAdd(&acc[(pv[u] & (BN - 1)) * ASTRIDE + f], v[u]);
    }
    for (; e < s1; e += G) {
        int pv = pairs[e];
        atomicAdd(&acc[(pv & (BN - 1)) * ASTRIDE + f], hs1[(size_t)(pv >> NB_BITS) * 16 + f]);
    }
    __syncthreads();
    int nbase = b << NB_BITS;
    float bbf = b1[f], wwf = W2[f];
    for (int nl = t >> 4; nl < BN; nl += G) {
        int n = nbase + nl;
        float d = 0.f, p = 0.f;
        if (n < N) {
            d = dis[n];
            float self = hs1[(size_t)n * 16 + f];
            p = fmaxf(d * (acc[nl * ASTRIDE + f] + self) + bbf, 0.f) * wwf;
        }
        p += __shfl_xor(p, 1);
        p += __shfl_xor(p, 2);
        p += __shfl_xor(p, 4);
        p += __shfl_xor(p, 8);
        if (f == 0 && n < N) hs2[n] = p * d;
    }
}

// layer-2: per-bucket LDS accumulate of hs2, 8x-unrolled, epilogue self+bias
__global__ void agg2_kernel(const int* __restrict__ pairs, const int* __restrict__ bstart,
                            const float* __restrict__ hs2, const float* __restrict__ dis,
                            const float* __restrict__ b2, float* __restrict__ out, int N) {
    __shared__ float acc[BN];
    int b = blockIdx.x, t = threadIdx.x;
    for (int i = t; i < BN; i += AGG_TPB) acc[i] = 0.f;
    __syncthreads();
    int s0 = bstart[b], s1 = bstart[b + 1];
    int e = s0 + t;
    for (; e + (UF - 1) * AGG_TPB < s1; e += UF * AGG_TPB) {
        int pv[UF];
        float v[UF];
#pragma unroll
        for (int u = 0; u < UF; u++) pv[u] = pairs[e + u * AGG_TPB];
#pragma unroll
        for (int u = 0; u < UF; u++) v[u] = hs2[pv[u] >> NB_BITS];
#pragma unroll
        for (int u = 0; u < UF; u++) atomicAdd(&acc[pv[u] & (BN - 1)], v[u]);
    }
    for (; e < s1; e += AGG_TPB) {
        int pv = pairs[e];
        atomicAdd(&acc[pv & (BN - 1)], hs2[pv >> NB_BITS]);
    }
    __syncthreads();
    int nbase = b << NB_BITS;
    for (int i = t; i < BN; i += AGG_TPB) {
        int n = nbase + i;
        if (n < N) out[n] = dis[n] * (acc[i] + hs2[n]) + b2[0];
    }
}

extern "C" void kernel_launch(void* const* d_in, const int* in_sizes, int n_in,
                              void* d_out, int out_size, void* d_ws, size_t ws_size,
                              hipStream_t stream) {
    const float* x = (const float*)d_in[0];
    const int* edge_index = (const int*)d_in[1];
    const float* W1 = (const float*)d_in[2];
    const float* b1 = (const float*)d_in[3];
    const float* W2 = (const float*)d_in[4];
    const float* b2 = (const float*)d_in[5];
    float* out = (float*)d_out;

    const int N = in_sizes[0] / 18;
    const int E = in_sizes[1] / 2;
    const int* src = edge_index;
    const int* dst = edge_index + E;
    const int NB = (N + BN - 1) / BN;  // 489

    // ws layout (4B words): pairs[E], hs1[16N], hs2[N], dis[N],
    // bstart[BN+1], cursor[BN], bcnt[BN]  ~= 34 MB
    int* ws = (int*)d_ws;
    int* pairs = ws;
    float* hs1 = (float*)(ws + (size_t)E);
    float* hs2 = hs1 + (size_t)16 * N;
    float* dis = hs2 + N;
    int* bstart = (int*)(dis + N);
    int* cursor = bstart + BN + 1;
    int* bcnt = cursor + BN;

    hipMemsetAsync(bcnt, 0, BN * sizeof(int), stream);

    int binBlocks = (E + BIN_CHUNK - 1) / BIN_CHUNK;  // 489
    int nBlocksN = (N + 255) / 256;

    bhist_kernel<<<binBlocks, BIN_TPB, 0, stream>>>(dst, bcnt, E);
    bscan_kernel<<<1, BN, 0, stream>>>(bcnt, bstart, cursor);
    bplace_kernel<<<binBlocks, BIN_TPB, 0, stream>>>(src, dst, cursor, pairs, E);
    degdis_kernel<<<NB, 512, 0, stream>>>(pairs, bstart, dis, N);
    h1_kernel<<<nBlocksN, 256, 0, stream>>>(x, W1, dis, hs1, N);
    agg1_kernel<<<NB, AGG_TPB, 0, stream>>>(pairs, bstart, hs1, dis, b1, W2, hs2, N);
    agg2_kernel<<<NB, AGG_TPB, 0, stream>>>(pairs, bstart, hs2, dis, b2, out, N);
}